// Round 12
// baseline (464.791 us; speedup 1.0000x reference)
//
#include <hip/hip_runtime.h>

#define N_NODES 50000
#define N_EDGES 800000
#define IN_DIM  162
#define HID     256
#define KPAD1   192   // IN_DIM padded to multiple of 32

typedef __bf16 bf16;
typedef __bf16 bf16x8 __attribute__((ext_vector_type(8)));
typedef __bf16 bf16x4 __attribute__((ext_vector_type(4)));
typedef float  f32x4  __attribute__((ext_vector_type(4)));
typedef float  f32x8  __attribute__((ext_vector_type(8)));
typedef float  f32x16 __attribute__((ext_vector_type(16)));

// ---------------------------------------------------------------------------
// Frag-major weight pack: Wf element E holds the MFMA B-frag element
//   fb = jg*2+kk, E = ((ks*16 + fb)*64 + lane)*8 + e
//   -> W[k][n], n = jg*32 + (lane&31), k = ks*32 + kk*16 + (lane>>5)*8 + e
__device__ __forceinline__ void wf_one(const float* W, bf16* Wf, int K, int E)
{
    int e    = E & 7;
    int lane = (E >> 3) & 63;
    int fb   = (E >> 9) & 15;
    int ks   = E >> 13;
    int n = (fb >> 1) * 32 + (lane & 31);
    int k = ks * 32 + (fb & 1) * 16 + (lane >> 5) * 8 + e;
    Wf[E] = (k < K) ? (bf16)W[(size_t)k * HID + n] : (bf16)0.0f;
}

// ---------------------------------------------------------------------------
// prep_all: one launch, partitioned by block.
//   [0, WTB)       : frag-major weight packs (4 matrices)
//   [WTB, +FPB)    : feat prep (single read, register colsum, coalesced writes)
//   [.., +DGB)     : degree histogram
#define WTB  ((HID * KPAD1 + 3 * HID * HID + 255) / 256)          // 960
#define FPB  ((N_NODES + 63) / 64)                                // 782
#define DGB  (N_EDGES / 256)                                      // 3125

__global__ void prep_all(const float* __restrict__ m1aw, const float* __restrict__ m1bw,
                         const float* __restrict__ m2aw, const float* __restrict__ m2bw,
                         bf16* __restrict__ Wf1, bf16* __restrict__ Wf2,
                         bf16* __restrict__ Wf3, bf16* __restrict__ Wf4,
                         const float* __restrict__ feat, bf16* __restrict__ featbf,
                         float* __restrict__ colsum8,
                         const int* __restrict__ dst, int* __restrict__ deg)
{
    __shared__ bf16  tile[64][208];   // padded rows (416B stride)
    __shared__ float pcs[4][KPAD1];   // per-rowgroup colsum partials

    const int b   = blockIdx.x;
    const int tid = threadIdx.x;

    if (b < WTB) {
        const int R1 = HID * KPAD1;
        const int R2 = HID * HID;
        int idx = b * 256 + tid;
        if (idx < R1)                 wf_one(m1aw, Wf1, IN_DIM, idx);
        else if (idx < R1 + R2)       wf_one(m1bw, Wf2, HID, idx - R1);
        else if (idx < R1 + 2 * R2)   wf_one(m2aw, Wf3, HID, idx - R1 - R2);
        else if (idx < R1 + 3 * R2)   wf_one(m2bw, Wf4, HID, idx - R1 - 2 * R2);
        return;
    }
    if (b < WTB + FPB) {
        const int fp = b - WTB;
        const int r0 = fp * 64;

        // phase A: thread t<192 owns column-quad ch=t%48 for row-group rg=t/48
        if (tid < 192) {
            const int ch = tid % 48;
            const int rg = tid / 48;
            const int c4 = ch * 4;
            float a0 = 0.0f, a1 = 0.0f, a2 = 0.0f, a3 = 0.0f;
#pragma unroll 4
            for (int k = 0; k < 16; ++k) {
                const int rl = rg * 16 + k;
                const int r  = r0 + rl;
                bf16x4 o;
                if (r < N_NODES) {
                    const float* fr = feat + (size_t)r * IN_DIM;
                    float f0 = (c4 + 0 < IN_DIM) ? fr[c4 + 0] : 0.0f;
                    float f1 = (c4 + 1 < IN_DIM) ? fr[c4 + 1] : 0.0f;
                    float f2 = (c4 + 2 < IN_DIM) ? fr[c4 + 2] : 0.0f;
                    float f3 = (c4 + 3 < IN_DIM) ? fr[c4 + 3] : 0.0f;
                    a0 += f0; a1 += f1; a2 += f2; a3 += f3;
                    o[0] = (bf16)f0; o[1] = (bf16)f1; o[2] = (bf16)f2; o[3] = (bf16)f3;
                } else {
#pragma unroll
                    for (int j = 0; j < 4; ++j) o[j] = (bf16)0.0f;
                }
                *(bf16x4*)(&tile[rl][c4]) = o;
            }
            pcs[rg][c4 + 0] = a0;
            pcs[rg][c4 + 1] = a1;
            pcs[rg][c4 + 2] = a2;
            pcs[rg][c4 + 3] = a3;
        }
        __syncthreads();

        // phase B: group-major coalesced writes: 8 groups x 64 rows x 24 cols
#pragma unroll
        for (int i = 0; i < 6; ++i) {
            int m  = i * 256 + tid;           // [0, 1536)
            int g  = m / 192;
            int wg = m - g * 192;
            int eo = wg * 8;
            int rl = eo / 24;
            int cc = eo - rl * 24;
            int r  = r0 + rl;
            if (r < N_NODES) {
                bf16x8 o = *(const bf16x8*)(&tile[rl][g * 24 + cc]);
                *(bf16x8*)(featbf + ((size_t)g * N_NODES + r0) * 24 + (size_t)rl * 24 + cc) = o;
            }
        }

        // phase C: combine 4 row-group partials, one global atomic per column
        if (tid < IN_DIM) {
            float s = pcs[0][tid] + pcs[1][tid] + pcs[2][tid] + pcs[3][tid];
            atomicAdd(&colsum8[(fp & 7) * KPAD1 + tid], s);
        }
        return;
    }
    {
        int e = (b - WTB - FPB) * 256 + tid;
        atomicAdd(&deg[dst[e]], 1);
    }
}

// ---------------------------------------------------------------------------
// csr_scan: full exclusive scan of deg in ONE kernel (1 block x 1024 thr).
// Replaces block_degsum + scan_bsum + block_scan_write (3 dispatches).
// Thread t holds 52 ints (13 x int4) in registers; Hillis-Steele block scan
// (same proven shape as the old scan_bsum) over the 1024 per-thread sums.
#define SCT 52
__launch_bounds__(1024)
__global__ void csr_scan(const int* __restrict__ deg,
                         int* __restrict__ rowptr, int* __restrict__ cursor)
{
    __shared__ int s[1024];
    const int t = threadIdx.x;
    const int base = t * SCT;
    int4 v[13];
    int sum = 0;
#pragma unroll
    for (int i = 0; i < 13; ++i) {
        int idx = base + i * 4;
        int4 q = *(const int4*)(deg + idx);   // may read padded ws tail (masked)
        q.x = (idx + 0 < N_NODES) ? q.x : 0;
        q.y = (idx + 1 < N_NODES) ? q.y : 0;
        q.z = (idx + 2 < N_NODES) ? q.z : 0;
        q.w = (idx + 3 < N_NODES) ? q.w : 0;
        v[i] = q;
        sum += q.x + q.y + q.z + q.w;
    }
    s[t] = sum;
    __syncthreads();
    for (int off = 1; off < 1024; off <<= 1) {
        int u = (t >= off) ? s[t - off] : 0;
        __syncthreads();
        s[t] += u;
        __syncthreads();
    }
    int run = s[t] - sum;   // exclusive prefix of this thread's range
#pragma unroll
    for (int i = 0; i < 13; ++i) {
        int idx = base + i * 4;
        int4 q = v[i];
        if (idx + 0 < N_NODES) { rowptr[idx + 0] = run; cursor[idx + 0] = run; run += q.x; }
        if (idx + 1 < N_NODES) { rowptr[idx + 1] = run; cursor[idx + 1] = run; run += q.y; }
        if (idx + 2 < N_NODES) { rowptr[idx + 2] = run; cursor[idx + 2] = run; run += q.z; }
        if (idx + 3 < N_NODES) { rowptr[idx + 3] = run; cursor[idx + 3] = run; run += q.w; }
    }
    if (t == 1023) rowptr[N_NODES] = N_EDGES;
}

// ---------------------------------------------------------------------------
// csr_fill v2: bucketed + XCD-pinned (write-amplification fix, r11-verified).
#define CFT 2048
#define NRANGE ((N_NODES + 7) / 8)   // 6250

__global__ void csr_fill_b(const int* __restrict__ src, const int* __restrict__ dst,
                           int* __restrict__ cursor, int* __restrict__ csr_src)
{
    const int g    = blockIdx.x & 7;
    const int tile = blockIdx.x >> 3;
    const int lo   = g * NRANGE;
    const int hi   = lo + NRANGE;
    const int e0   = tile * CFT;
#pragma unroll
    for (int i = 0; i < CFT / 256; ++i) {
        int e = e0 + i * 256 + threadIdx.x;
        if (e < N_EDGES) {
            int d = dst[e];
            if (d >= lo && d < hi) {
                int p = atomicAdd(&cursor[d], 1);
                csr_src[p] = src[e];
            }
        }
    }
}

// ---------------------------------------------------------------------------
// Gather v5: tiled [8][N][CHUNK] input/output, XCD-pinned groups, in-register
// index list, masked unrolled row-load blocks.
template<int CHUNK, int NACT>
__launch_bounds__(256)
__global__ void gather_v5(const bf16* __restrict__ xin,
                          const int* __restrict__ rowptr,
                          const int* __restrict__ csr_src,
                          bf16* __restrict__ xout)
{
    const int g    = blockIdx.x & 7;
    const int tile = blockIdx.x >> 3;
    const int wv   = threadIdx.x >> 6;
    const int lane = threadIdx.x & 63;
    const int q    = lane >> 4;          // node within wave 0..3
    const int j    = lane & 15;          // idx slot
    const int e    = j >> 2;             // stripe 0..3
    const int c4   = j & 3;              // 16B chunk
    const int n    = tile * 16 + wv * 4 + q;
    const bool valid = (n < N_NODES);
    const bool act   = (c4 < NACT);
    const int  ce    = c4 * 8;
    const bf16* base = xin + (size_t)g * N_NODES * CHUNK;

    int r0 = 0, deg = 0;
    if (valid) {
        r0  = rowptr[n];
        deg = rowptr[n + 1] - r0;
    }

    int a0 = r0 + j;        if (a0 > N_EDGES - 1) a0 = N_EDGES - 1;
    int a1 = r0 + 16 + j;   if (a1 > N_EDGES - 1) a1 = N_EDGES - 1;
    const int i0 = csr_src[a0];
    int i1 = 0;
    if (deg > 16) i1 = csr_src[a1];   // only needed when block 2 fires

    f32x8 acc;
#pragma unroll
    for (int t = 0; t < 8; ++t) acc[t] = 0.0f;
    if (valid && e == 0 && act) {
        bf16x8 t0 = *(const bf16x8*)(base + (size_t)n * CHUNK + ce);
#pragma unroll
        for (int t = 0; t < 8; ++t) acc[t] = (float)t0[t];
    }

    const int lb = lane & ~3;

    // ---- block 1: positions 4e + k ----
    {
        const int s0 = __shfl(i0, lb + 0, 64);
        const int s1 = __shfl(i0, lb + 1, 64);
        const int s2 = __shfl(i0, lb + 2, 64);
        const int s3 = __shfl(i0, lb + 3, 64);
        const int p0 = 4 * e;
        if (act) {
            bf16x8 u0 = *(const bf16x8*)(base + (size_t)s0 * CHUNK + ce);
            bf16x8 u1 = *(const bf16x8*)(base + (size_t)s1 * CHUNK + ce);
            bf16x8 u2 = *(const bf16x8*)(base + (size_t)s2 * CHUNK + ce);
            bf16x8 u3 = *(const bf16x8*)(base + (size_t)s3 * CHUNK + ce);
            if (p0 + 0 < deg) {
#pragma unroll
                for (int t = 0; t < 8; ++t) acc[t] += (float)u0[t];
            }
            if (p0 + 1 < deg) {
#pragma unroll
                for (int t = 0; t < 8; ++t) acc[t] += (float)u1[t];
            }
            if (p0 + 2 < deg) {
#pragma unroll
                for (int t = 0; t < 8; ++t) acc[t] += (float)u2[t];
            }
            if (p0 + 3 < deg) {
#pragma unroll
                for (int t = 0; t < 8; ++t) acc[t] += (float)u3[t];
            }
        }
    }

    // ---- block 2: positions 16 + 4e + k, stripe-gated ----
    {
        const int s0 = __shfl(i1, lb + 0, 64);
        const int s1 = __shfl(i1, lb + 1, 64);
        const int s2 = __shfl(i1, lb + 2, 64);
        const int s3 = __shfl(i1, lb + 3, 64);
        const int p0 = 16 + 4 * e;
        if (act && p0 < deg) {
            bf16x8 u0 = *(const bf16x8*)(base + (size_t)s0 * CHUNK + ce);
            bf16x8 u1 = *(const bf16x8*)(base + (size_t)s1 * CHUNK + ce);
            bf16x8 u2 = *(const bf16x8*)(base + (size_t)s2 * CHUNK + ce);
            bf16x8 u3 = *(const bf16x8*)(base + (size_t)s3 * CHUNK + ce);
            {
#pragma unroll
                for (int t = 0; t < 8; ++t) acc[t] += (float)u0[t];
            }
            if (p0 + 1 < deg) {
#pragma unroll
                for (int t = 0; t < 8; ++t) acc[t] += (float)u1[t];
            }
            if (p0 + 2 < deg) {
#pragma unroll
                for (int t = 0; t < 8; ++t) acc[t] += (float)u2[t];
            }
            if (p0 + 3 < deg) {
#pragma unroll
                for (int t = 0; t < 8; ++t) acc[t] += (float)u3[t];
            }
        }
    }

    // ---- rare tail: deg > 32 ----
    for (int p = 32 + e; p < deg; p += 4) {
        const int s = csr_src[r0 + p];
        if (act) {
            bf16x8 u = *(const bf16x8*)(base + (size_t)s * CHUNK + ce);
#pragma unroll
            for (int t = 0; t < 8; ++t) acc[t] += (float)u[t];
        }
    }

#pragma unroll
    for (int t = 0; t < 8; ++t) {
        acc[t] += __shfl_xor(acc[t], 4, 64);
        acc[t] += __shfl_xor(acc[t], 8, 64);
    }

    if (valid && e == 0 && act) {
        bf16x8 o;
#pragma unroll
        for (int t = 0; t < 8; ++t) o[t] = (bf16)acc[t];
        __builtin_nontemporal_store(o,
            (bf16x8*)(xout + ((size_t)g * N_NODES + n) * CHUNK + ce));
    }
}

// ---------------------------------------------------------------------------
// Fused GIN MLP "gemm_mlp32": out = relu(relu(X@W1+b1)@W2+b2).
// 32-row blocks, 8 waves; wave w owns cols [w*32, w*32+32) -> 32x32 per wave.
// Grid = 1563 blocks = 12512 waves (TLP-maximizing; r7/r8 A/B evidence).
// B-frags coalesced from frag-major Wf (L2-resident); no K-loop barriers.
// H in LDS (16KB), (row&31)<<4 XOR swizzle. colsum 8-slotted [8][HID].
template<int KPAD, int ACHUNK, int OCHUNK>
__launch_bounds__(512)
__global__ void gemm_mlp32(const bf16* __restrict__ X,
                           const bf16* __restrict__ Wf1,
                           const float* __restrict__ bias1,
                           const bf16* __restrict__ Wf2,
                           const float* __restrict__ bias2,
                           bf16* __restrict__ out_bf,
                           float* __restrict__ colsum8,  // [8][HID] or null
                           int M)
{
    __shared__ __align__(128) bf16 sH[32 * HID];   // 16 KB

    const int tid  = threadIdx.x;
    const int w    = tid >> 6;     // col group 0..7
    const int lane = tid & 63;
    const int p    = lane >> 5;
    const int cn   = lane & 31;
    const int m_base = blockIdx.x * 32;

    int arow = m_base + cn;
    if (arow >= M) arow = M - 1;   // clamp (stores guarded)

    f32x16 acc;
#pragma unroll
    for (int r = 0; r < 16; ++r) acc[r] = 0.0f;

    // ---- phase 1: acc = X @ W1 (barrier-free) ----
    constexpr int T1 = KPAD / 16;
#pragma unroll
    for (int t = 0; t < T1; ++t) {
        bf16x8 a;
        {
            const int e = t * 16 + p * 8;
            if constexpr (ACHUNK == 0) {
                a = *(const bf16x8*)(X + (size_t)arow * KPAD + e);
            } else {
                const int gch = e / ACHUNK;
                const int off = e - gch * ACHUNK;
                a = *(const bf16x8*)(X + ((size_t)gch * N_NODES + arow) * ACHUNK + off);
            }
        }
        bf16x8 b = *(const bf16x8*)(Wf1 + ((((t >> 1) * 16 + w * 2 + (t & 1)) * 64) + lane) * 8);
        acc = __builtin_amdgcn_mfma_f32_32x32x16_bf16(a, b, acc, 0, 0, 0);
    }

    // ---- epilogue 1: H = relu(acc + b1) -> LDS, (row&31)<<4 swizzle ----
    char* sHb = (char*)sH;
    {
        const int col = w * 32 + cn;
        const float bv = bias1[col];
#pragma unroll
        for (int r = 0; r < 16; ++r) {
            const int rowl = (r & 3) + 8 * (r >> 2) + 4 * p;   // 0..31
            float v = acc[r] + bv;
            v = v > 0.0f ? v : 0.0f;
            int ba = rowl * (HID * 2) + col * 2;
            ba ^= (rowl & 31) << 4;
            *(bf16*)(sHb + ba) = (bf16)v;
        }
    }
    __syncthreads();

    // ---- phase 2: acc = H @ W2 (A from LDS, barrier-free) ----
#pragma unroll
    for (int r = 0; r < 16; ++r) acc[r] = 0.0f;

    const int hrow = cn;
    const int hswz = (hrow & 31) << 4;
    constexpr int T2 = HID / 16;
#pragma unroll
    for (int t = 0; t < T2; ++t) {
        const int kb = (t * 16 + p * 8) * 2;
        bf16x8 a = *(const bf16x8*)(sHb + ((hrow * (HID * 2) + kb) ^ hswz));
        bf16x8 b = *(const bf16x8*)(Wf2 + ((((t >> 1) * 16 + w * 2 + (t & 1)) * 64) + lane) * 8);
        acc = __builtin_amdgcn_mfma_f32_32x32x16_bf16(a, b, acc, 0, 0, 0);
    }

    // ---- epilogue 2: bias2 + relu + store + slotted colsum ----
    {
        const int col = w * 32 + cn;
        const float bv = bias2[col];
        float part = 0.0f;
#pragma unroll
        for (int r = 0; r < 16; ++r) {
            int rl = (r & 3) + 8 * (r >> 2) + 4 * p;
            int mo = m_base + rl;
            if (mo < M) {
                float v = acc[r] + bv;
                v = v > 0.0f ? v : 0.0f;
                if constexpr (OCHUNK == 0)
                    out_bf[(size_t)mo * HID + col] = (bf16)v;
                else
                    out_bf[((size_t)w * N_NODES + mo) * OCHUNK + cn] = (bf16)v;
                part += v;
            }
        }
        if (colsum8) {
            part += __shfl_xor(part, 32, 64);   // combine the two p-halves
            if (p == 0) atomicAdd(&colsum8[(blockIdx.x & 7) * HID + col], part);
        }
    }
}

// ---------------------------------------------------------------------------
// final_gh: graph head + final add, ONE kernel. Every block redundantly
// computes gvec (identical deterministic math, LDS-resident weights via L2),
// then grid-strides out[n,c] = node2[n,c] + gvec[c].
__launch_bounds__(256)
__global__ void final_gh(const float* __restrict__ cs0_8,
                         const float* __restrict__ cs1_8,
                         const float* __restrict__ cs2_8,
                         const float* __restrict__ g0w, const float* __restrict__ g0b,
                         const float* __restrict__ g1w, const float* __restrict__ g1b,
                         const float* __restrict__ g2w, const float* __restrict__ g2b,
                         const float* __restrict__ glw, const float* __restrict__ glb,
                         const bf16* __restrict__ node2,
                         float* __restrict__ out)
{
    __shared__ float v0[IN_DIM], v1[HID], v2[HID], gs[HID], gv[HID];
    const int t = threadIdx.x;
    if (t < IN_DIM) {
        float s = 0.0f;
#pragma unroll
        for (int i = 0; i < 8; ++i) s += cs0_8[i * KPAD1 + t];
        v0[t] = s;
    }
    {
        float s1 = 0.0f, s2 = 0.0f;
#pragma unroll
        for (int i = 0; i < 8; ++i) {
            s1 += cs1_8[i * HID + t];
            s2 += cs2_8[i * HID + t];
        }
        v1[t] = s1;
        v2[t] = s2;
    }
    __syncthreads();

    float a0 = 0.0f, a1 = 0.0f, a2 = 0.0f;
    for (int k = 0; k < IN_DIM; ++k) a0 += v0[k] * g0w[k * HID + t];
    for (int k = 0; k < HID; ++k) {
        a1 += v1[k] * g1w[k * HID + t];
        a2 += v2[k] * g2w[k * HID + t];
    }
    float e0 = fmaxf(a0 + g0b[t], 0.0f);
    float e1 = fmaxf(a1 + g1b[t], 0.0f);
    float e2 = fmaxf(a2 + g2b[t], 0.0f);
    gs[t] = e0 + e1 + e2;
    __syncthreads();

    float a3 = 0.0f;
    for (int k = 0; k < HID; ++k) a3 += gs[k] * glw[k * HID + t];
    gv[t] = fmaxf(a3 + glb[t], 0.0f);
    __syncthreads();

    const int total = N_NODES * HID / 4;
    for (int q = blockIdx.x * 256 + t; q < total; q += gridDim.x * 256) {
        size_t bb = (size_t)q * 4;
        int c = (int)(bb & (HID - 1));
        bf16x4 v = *(const bf16x4*)(node2 + bb);
        f32x4 o;
#pragma unroll
        for (int jj = 0; jj < 4; ++jj) o[jj] = (float)v[jj] + gv[c + jj];
        *(f32x4*)(out + bb) = o;
    }
}

// ---------------------------------------------------------------------------
extern "C" void kernel_launch(void* const* d_in, const int* in_sizes, int n_in,
                              void* d_out, int out_size, void* d_ws, size_t ws_size,
                              hipStream_t stream)
{
    const float* feat = (const float*)d_in[0];
    const int*   ei   = (const int*)d_in[1];
    const int*   src  = ei;
    const int*   dst  = ei + N_EDGES;
    const float* g0w = (const float*)d_in[2],  *g0b = (const float*)d_in[3];
    const float* g1w = (const float*)d_in[4],  *g1b = (const float*)d_in[5];
    const float* g2w = (const float*)d_in[6],  *g2b = (const float*)d_in[7];
    const float* glw = (const float*)d_in[8],  *glb = (const float*)d_in[9];
    const float* m1aw = (const float*)d_in[10], *m1ab = (const float*)d_in[11];
    const float* m1bw = (const float*)d_in[12], *m1bb = (const float*)d_in[13];
    const float* m2aw = (const float*)d_in[14], *m2ab = (const float*)d_in[15];
    const float* m2bw = (const float*)d_in[16], *m2bb = (const float*)d_in[17];
    float* out = (float*)d_out;

    char* ws = (char*)d_ws;
    size_t off = 0;
    auto alloc = [&](size_t bytes) -> void* {
        void* p = ws + off;
        off += (bytes + 255) & ~(size_t)255;
        return p;
    };
    bf16*  featbf = (bf16*)alloc((size_t)N_NODES * KPAD1 * 2);   // tiled [8][N][24]
    bf16*  xsum  = (bf16*) alloc((size_t)N_NODES * KPAD1 * 2);   // tiled [8][N][24]
    bf16*  y2    = (bf16*) alloc((size_t)N_NODES * HID * 2);     // tiled [8][N][32]
    bf16*  node2 = (bf16*) alloc((size_t)N_NODES * HID * 2);     // linear
    bf16*  node1 = (bf16*) alloc((size_t)N_NODES * HID * 2);     // tiled [8][N][32]
    bf16*  Wf1   = (bf16*) alloc((size_t)HID * KPAD1 * 2);       // frag-major
    bf16*  Wf2   = (bf16*) alloc((size_t)HID * HID * 2);
    bf16*  Wf3   = (bf16*) alloc((size_t)HID * HID * 2);
    bf16*  Wf4   = (bf16*) alloc((size_t)HID * HID * 2);
    // deg + csums adjacent -> single memset
    int*   deg   = (int*)  alloc((size_t)N_NODES * 4);           // 200192 padded
    float* csums = (float*)alloc((8 * KPAD1 + 16 * HID) * 4);    // 22528
    int*   rowptr  = (int*)alloc((size_t)(N_NODES + 1) * 4);
    int*   cursor  = (int*)alloc((size_t)N_NODES * 4);
    int*   csr_src = (int*)alloc((size_t)N_EDGES * 4);
    float* colsum0_8 = csums;                          // 8 x 192 slots
    float* colsum1_8 = csums + 8 * KPAD1;              // 8 x 256 slots
    float* colsum2_8 = csums + 8 * KPAD1 + 8 * HID;    // 8 x 256 slots

    const size_t deg_pad = (((size_t)N_NODES * 4) + 255) & ~(size_t)255;
    hipMemsetAsync(deg, 0, deg_pad + (8 * KPAD1 + 16 * HID) * 4, stream);

    // all independent preprocessing in one launch
    prep_all<<<WTB + FPB + DGB, 256, 0, stream>>>(
        m1aw, m1bw, m2aw, m2bw, Wf1, Wf2, Wf3, Wf4,
        feat, featbf, colsum0_8, dst, deg);

    // CSR scan: single kernel
    csr_scan<<<1, 1024, 0, stream>>>(deg, rowptr, cursor);
    // bucketed, XCD-pinned fill
    csr_fill_b<<<((N_EDGES + CFT - 1) / CFT) * 8, 256, 0, stream>>>(src, dst, cursor, csr_src);

    const int gtiles = (N_NODES + 15) / 16;   // 4 nodes/wave x 4 waves
    // xsum = bf16(feat + gather(feat))
    gather_v5<24, 3><<<gtiles * 8, 256, 0, stream>>>(featbf, rowptr, csr_src, xsum);

    const int gblocks = (N_NODES + 31) / 32;   // 1563
    // node1 = relu(relu(xsum@W1+b1)@W2+b2), colsum1 fused
    gemm_mlp32<KPAD1, 24, 32><<<gblocks, 512, 0, stream>>>(
        xsum, Wf1, m1ab, Wf2, m1bb, node1, colsum1_8, N_NODES);
    // y2 = bf16(node1 + gather(node1))
    gather_v5<32, 4><<<gtiles * 8, 256, 0, stream>>>(node1, rowptr, csr_src, y2);
    // node2 = relu(relu(y2@W3+b3)@W4+b4), colsum2 fused
    gemm_mlp32<HID, 32, 0><<<gblocks, 512, 0, stream>>>(
        y2, Wf3, m2ab, Wf4, m2bb, node2, colsum2_8, N_NODES);
    // graph head + broadcast add, one kernel
    final_gh<<<256, 256, 0, stream>>>(colsum0_8, colsum1_8, colsum2_8,
                                      g0w, g0b, g1w, g1b, g2w, g2b, glw, glb,
                                      node2, out);
    (void)in_sizes; (void)n_in; (void)out_size; (void)ws_size;
}

// Round 13
// 463.261 us; speedup vs baseline: 1.0033x; 1.0033x over previous
//
#include <hip/hip_runtime.h>

#define N_NODES 50000
#define N_EDGES 800000
#define IN_DIM  162
#define HID     256
#define KPAD1   192   // IN_DIM padded to multiple of 32

typedef __bf16 bf16;
typedef __bf16 bf16x8 __attribute__((ext_vector_type(8)));
typedef __bf16 bf16x4 __attribute__((ext_vector_type(4)));
typedef float  f32x4  __attribute__((ext_vector_type(4)));
typedef float  f32x8  __attribute__((ext_vector_type(8)));
typedef float  f32x16 __attribute__((ext_vector_type(16)));

// ---------------------------------------------------------------------------
// Frag-major weight pack: Wf element E holds the MFMA B-frag element
//   fb = jg*2+kk, E = ((ks*16 + fb)*64 + lane)*8 + e
//   -> W[k][n], n = jg*32 + (lane&31), k = ks*32 + kk*16 + (lane>>5)*8 + e
__device__ __forceinline__ void wf_one(const float* W, bf16* Wf, int K, int E)
{
    int e    = E & 7;
    int lane = (E >> 3) & 63;
    int fb   = (E >> 9) & 15;
    int ks   = E >> 13;
    int n = (fb >> 1) * 32 + (lane & 31);
    int k = ks * 32 + (fb & 1) * 16 + (lane >> 5) * 8 + e;
    Wf[E] = (k < K) ? (bf16)W[(size_t)k * HID + n] : (bf16)0.0f;
}

// ---------------------------------------------------------------------------
// prep_all: one launch, partitioned by block.
#define WTB  ((HID * KPAD1 + 3 * HID * HID + 255) / 256)          // 960
#define FPB  ((N_NODES + 63) / 64)                                // 782
#define DGB  (N_EDGES / 256)                                      // 3125

__global__ void prep_all(const float* __restrict__ m1aw, const float* __restrict__ m1bw,
                         const float* __restrict__ m2aw, const float* __restrict__ m2bw,
                         bf16* __restrict__ Wf1, bf16* __restrict__ Wf2,
                         bf16* __restrict__ Wf3, bf16* __restrict__ Wf4,
                         const float* __restrict__ feat, bf16* __restrict__ featbf,
                         float* __restrict__ colsum8,
                         const int* __restrict__ dst, int* __restrict__ deg)
{
    __shared__ bf16  tile[64][208];   // padded rows (416B stride)
    __shared__ float pcs[4][KPAD1];   // per-rowgroup colsum partials

    const int b   = blockIdx.x;
    const int tid = threadIdx.x;

    if (b < WTB) {
        const int R1 = HID * KPAD1;
        const int R2 = HID * HID;
        int idx = b * 256 + tid;
        if (idx < R1)                 wf_one(m1aw, Wf1, IN_DIM, idx);
        else if (idx < R1 + R2)       wf_one(m1bw, Wf2, HID, idx - R1);
        else if (idx < R1 + 2 * R2)   wf_one(m2aw, Wf3, HID, idx - R1 - R2);
        else if (idx < R1 + 3 * R2)   wf_one(m2bw, Wf4, HID, idx - R1 - 2 * R2);
        return;
    }
    if (b < WTB + FPB) {
        const int fp = b - WTB;
        const int r0 = fp * 64;

        // phase A: thread t<192 owns column-quad ch=t%48 for row-group rg=t/48
        if (tid < 192) {
            const int ch = tid % 48;
            const int rg = tid / 48;
            const int c4 = ch * 4;
            float a0 = 0.0f, a1 = 0.0f, a2 = 0.0f, a3 = 0.0f;
#pragma unroll 4
            for (int k = 0; k < 16; ++k) {
                const int rl = rg * 16 + k;
                const int r  = r0 + rl;
                bf16x4 o;
                if (r < N_NODES) {
                    const float* fr = feat + (size_t)r * IN_DIM;
                    float f0 = (c4 + 0 < IN_DIM) ? fr[c4 + 0] : 0.0f;
                    float f1 = (c4 + 1 < IN_DIM) ? fr[c4 + 1] : 0.0f;
                    float f2 = (c4 + 2 < IN_DIM) ? fr[c4 + 2] : 0.0f;
                    float f3 = (c4 + 3 < IN_DIM) ? fr[c4 + 3] : 0.0f;
                    a0 += f0; a1 += f1; a2 += f2; a3 += f3;
                    o[0] = (bf16)f0; o[1] = (bf16)f1; o[2] = (bf16)f2; o[3] = (bf16)f3;
                } else {
#pragma unroll
                    for (int j = 0; j < 4; ++j) o[j] = (bf16)0.0f;
                }
                *(bf16x4*)(&tile[rl][c4]) = o;
            }
            pcs[rg][c4 + 0] = a0;
            pcs[rg][c4 + 1] = a1;
            pcs[rg][c4 + 2] = a2;
            pcs[rg][c4 + 3] = a3;
        }
        __syncthreads();

        // phase B: group-major coalesced writes: 8 groups x 64 rows x 24 cols
#pragma unroll
        for (int i = 0; i < 6; ++i) {
            int m  = i * 256 + tid;           // [0, 1536)
            int g  = m / 192;
            int wg = m - g * 192;
            int eo = wg * 8;
            int rl = eo / 24;
            int cc = eo - rl * 24;
            int r  = r0 + rl;
            if (r < N_NODES) {
                bf16x8 o = *(const bf16x8*)(&tile[rl][g * 24 + cc]);
                *(bf16x8*)(featbf + ((size_t)g * N_NODES + r0) * 24 + (size_t)rl * 24 + cc) = o;
            }
        }

        // phase C: combine 4 row-group partials, one global atomic per column
        if (tid < IN_DIM) {
            float s = pcs[0][tid] + pcs[1][tid] + pcs[2][tid] + pcs[3][tid];
            atomicAdd(&colsum8[(fp & 7) * KPAD1 + tid], s);
        }
        return;
    }
    {
        int e = (b - WTB - FPB) * 256 + tid;
        atomicAdd(&deg[dst[e]], 1);
    }
}

// ---------------------------------------------------------------------------
// csr_scan: full exclusive scan of deg in ONE kernel (1 block x 1024 thr).
#define SCT 52
__launch_bounds__(1024)
__global__ void csr_scan(const int* __restrict__ deg,
                         int* __restrict__ rowptr, int* __restrict__ cursor)
{
    __shared__ int s[1024];
    const int t = threadIdx.x;
    const int base = t * SCT;
    int4 v[13];
    int sum = 0;
#pragma unroll
    for (int i = 0; i < 13; ++i) {
        int idx = base + i * 4;
        int4 q = *(const int4*)(deg + idx);   // may read padded ws tail (masked)
        q.x = (idx + 0 < N_NODES) ? q.x : 0;
        q.y = (idx + 1 < N_NODES) ? q.y : 0;
        q.z = (idx + 2 < N_NODES) ? q.z : 0;
        q.w = (idx + 3 < N_NODES) ? q.w : 0;
        v[i] = q;
        sum += q.x + q.y + q.z + q.w;
    }
    s[t] = sum;
    __syncthreads();
    for (int off = 1; off < 1024; off <<= 1) {
        int u = (t >= off) ? s[t - off] : 0;
        __syncthreads();
        s[t] += u;
        __syncthreads();
    }
    int run = s[t] - sum;   // exclusive prefix of this thread's range
#pragma unroll
    for (int i = 0; i < 13; ++i) {
        int idx = base + i * 4;
        int4 q = v[i];
        if (idx + 0 < N_NODES) { rowptr[idx + 0] = run; cursor[idx + 0] = run; run += q.x; }
        if (idx + 1 < N_NODES) { rowptr[idx + 1] = run; cursor[idx + 1] = run; run += q.y; }
        if (idx + 2 < N_NODES) { rowptr[idx + 2] = run; cursor[idx + 2] = run; run += q.z; }
        if (idx + 3 < N_NODES) { rowptr[idx + 3] = run; cursor[idx + 3] = run; run += q.w; }
    }
    if (t == 1023) rowptr[N_NODES] = N_EDGES;
}

// ---------------------------------------------------------------------------
// csr_fill v2: bucketed + XCD-pinned (write-amplification fix, r11-verified).
#define CFT 2048
#define NRANGE ((N_NODES + 7) / 8)   // 6250

__global__ void csr_fill_b(const int* __restrict__ src, const int* __restrict__ dst,
                           int* __restrict__ cursor, int* __restrict__ csr_src)
{
    const int g    = blockIdx.x & 7;
    const int tile = blockIdx.x >> 3;
    const int lo   = g * NRANGE;
    const int hi   = lo + NRANGE;
    const int e0   = tile * CFT;
#pragma unroll
    for (int i = 0; i < CFT / 256; ++i) {
        int e = e0 + i * 256 + threadIdx.x;
        if (e < N_EDGES) {
            int d = dst[e];
            if (d >= lo && d < hi) {
                int p = atomicAdd(&cursor[d], 1);
                csr_src[p] = src[e];
            }
        }
    }
}

// ---------------------------------------------------------------------------
// Gather v5: tiled [8][N][CHUNK] input/output, XCD-pinned groups, in-register
// index list, masked unrolled row-load blocks.
template<int CHUNK, int NACT>
__launch_bounds__(256)
__global__ void gather_v5(const bf16* __restrict__ xin,
                          const int* __restrict__ rowptr,
                          const int* __restrict__ csr_src,
                          bf16* __restrict__ xout)
{
    const int g    = blockIdx.x & 7;
    const int tile = blockIdx.x >> 3;
    const int wv   = threadIdx.x >> 6;
    const int lane = threadIdx.x & 63;
    const int q    = lane >> 4;          // node within wave 0..3
    const int j    = lane & 15;          // idx slot
    const int e    = j >> 2;             // stripe 0..3
    const int c4   = j & 3;              // 16B chunk
    const int n    = tile * 16 + wv * 4 + q;
    const bool valid = (n < N_NODES);
    const bool act   = (c4 < NACT);
    const int  ce    = c4 * 8;
    const bf16* base = xin + (size_t)g * N_NODES * CHUNK;

    int r0 = 0, deg = 0;
    if (valid) {
        r0  = rowptr[n];
        deg = rowptr[n + 1] - r0;
    }

    int a0 = r0 + j;        if (a0 > N_EDGES - 1) a0 = N_EDGES - 1;
    int a1 = r0 + 16 + j;   if (a1 > N_EDGES - 1) a1 = N_EDGES - 1;
    const int i0 = csr_src[a0];
    int i1 = 0;
    if (deg > 16) i1 = csr_src[a1];   // only needed when block 2 fires

    f32x8 acc;
#pragma unroll
    for (int t = 0; t < 8; ++t) acc[t] = 0.0f;
    if (valid && e == 0 && act) {
        bf16x8 t0 = *(const bf16x8*)(base + (size_t)n * CHUNK + ce);
#pragma unroll
        for (int t = 0; t < 8; ++t) acc[t] = (float)t0[t];
    }

    const int lb = lane & ~3;

    // ---- block 1: positions 4e + k ----
    {
        const int s0 = __shfl(i0, lb + 0, 64);
        const int s1 = __shfl(i0, lb + 1, 64);
        const int s2 = __shfl(i0, lb + 2, 64);
        const int s3 = __shfl(i0, lb + 3, 64);
        const int p0 = 4 * e;
        if (act) {
            bf16x8 u0 = *(const bf16x8*)(base + (size_t)s0 * CHUNK + ce);
            bf16x8 u1 = *(const bf16x8*)(base + (size_t)s1 * CHUNK + ce);
            bf16x8 u2 = *(const bf16x8*)(base + (size_t)s2 * CHUNK + ce);
            bf16x8 u3 = *(const bf16x8*)(base + (size_t)s3 * CHUNK + ce);
            if (p0 + 0 < deg) {
#pragma unroll
                for (int t = 0; t < 8; ++t) acc[t] += (float)u0[t];
            }
            if (p0 + 1 < deg) {
#pragma unroll
                for (int t = 0; t < 8; ++t) acc[t] += (float)u1[t];
            }
            if (p0 + 2 < deg) {
#pragma unroll
                for (int t = 0; t < 8; ++t) acc[t] += (float)u2[t];
            }
            if (p0 + 3 < deg) {
#pragma unroll
                for (int t = 0; t < 8; ++t) acc[t] += (float)u3[t];
            }
        }
    }

    // ---- block 2: positions 16 + 4e + k, stripe-gated ----
    {
        const int s0 = __shfl(i1, lb + 0, 64);
        const int s1 = __shfl(i1, lb + 1, 64);
        const int s2 = __shfl(i1, lb + 2, 64);
        const int s3 = __shfl(i1, lb + 3, 64);
        const int p0 = 16 + 4 * e;
        if (act && p0 < deg) {
            bf16x8 u0 = *(const bf16x8*)(base + (size_t)s0 * CHUNK + ce);
            bf16x8 u1 = *(const bf16x8*)(base + (size_t)s1 * CHUNK + ce);
            bf16x8 u2 = *(const bf16x8*)(base + (size_t)s2 * CHUNK + ce);
            bf16x8 u3 = *(const bf16x8*)(base + (size_t)s3 * CHUNK + ce);
            {
#pragma unroll
                for (int t = 0; t < 8; ++t) acc[t] += (float)u0[t];
            }
            if (p0 + 1 < deg) {
#pragma unroll
                for (int t = 0; t < 8; ++t) acc[t] += (float)u1[t];
            }
            if (p0 + 2 < deg) {
#pragma unroll
                for (int t = 0; t < 8; ++t) acc[t] += (float)u2[t];
            }
            if (p0 + 3 < deg) {
#pragma unroll
                for (int t = 0; t < 8; ++t) acc[t] += (float)u3[t];
            }
        }
    }

    // ---- rare tail: deg > 32 ----
    for (int p = 32 + e; p < deg; p += 4) {
        const int s = csr_src[r0 + p];
        if (act) {
            bf16x8 u = *(const bf16x8*)(base + (size_t)s * CHUNK + ce);
#pragma unroll
            for (int t = 0; t < 8; ++t) acc[t] += (float)u[t];
        }
    }

#pragma unroll
    for (int t = 0; t < 8; ++t) {
        acc[t] += __shfl_xor(acc[t], 4, 64);
        acc[t] += __shfl_xor(acc[t], 8, 64);
    }

    if (valid && e == 0 && act) {
        bf16x8 o;
#pragma unroll
        for (int t = 0; t < 8; ++t) o[t] = (bf16)acc[t];
        __builtin_nontemporal_store(o,
            (bf16x8*)(xout + ((size_t)g * N_NODES + n) * CHUNK + ce));
    }
}

// ---------------------------------------------------------------------------
// Fused GIN MLP "gemm_mlp32": out = relu(relu(X@W1+b1)@W2+b2).
// 32-row blocks, 8 waves; wave w owns cols [w*32, w*32+32) -> 32x32 per wave.
// Grid = 1563 blocks = 12512 waves (TLP-maximizing; r7/r8 A/B evidence).
// B-frags coalesced from frag-major Wf (L2-resident); no K-loop barriers.
// H in LDS (16KB), (row&31)<<4 XOR swizzle. colsum 8-slotted [8][HID].
template<int KPAD, int ACHUNK, int OCHUNK>
__launch_bounds__(512)
__global__ void gemm_mlp32(const bf16* __restrict__ X,
                           const bf16* __restrict__ Wf1,
                           const float* __restrict__ bias1,
                           const bf16* __restrict__ Wf2,
                           const float* __restrict__ bias2,
                           bf16* __restrict__ out_bf,
                           float* __restrict__ colsum8,  // [8][HID] or null
                           int M)
{
    __shared__ __align__(128) bf16 sH[32 * HID];   // 16 KB

    const int tid  = threadIdx.x;
    const int w    = tid >> 6;     // col group 0..7
    const int lane = tid & 63;
    const int p    = lane >> 5;
    const int cn   = lane & 31;
    const int m_base = blockIdx.x * 32;

    int arow = m_base + cn;
    if (arow >= M) arow = M - 1;   // clamp (stores guarded)

    f32x16 acc;
#pragma unroll
    for (int r = 0; r < 16; ++r) acc[r] = 0.0f;

    // ---- phase 1: acc = X @ W1 (barrier-free) ----
    constexpr int T1 = KPAD / 16;
#pragma unroll
    for (int t = 0; t < T1; ++t) {
        bf16x8 a;
        {
            const int e = t * 16 + p * 8;
            if constexpr (ACHUNK == 0) {
                a = *(const bf16x8*)(X + (size_t)arow * KPAD + e);
            } else {
                const int gch = e / ACHUNK;
                const int off = e - gch * ACHUNK;
                a = *(const bf16x8*)(X + ((size_t)gch * N_NODES + arow) * ACHUNK + off);
            }
        }
        bf16x8 b = *(const bf16x8*)(Wf1 + ((((t >> 1) * 16 + w * 2 + (t & 1)) * 64) + lane) * 8);
        acc = __builtin_amdgcn_mfma_f32_32x32x16_bf16(a, b, acc, 0, 0, 0);
    }

    // ---- epilogue 1: H = relu(acc + b1) -> LDS, (row&31)<<4 swizzle ----
    char* sHb = (char*)sH;
    {
        const int col = w * 32 + cn;
        const float bv = bias1[col];
#pragma unroll
        for (int r = 0; r < 16; ++r) {
            const int rowl = (r & 3) + 8 * (r >> 2) + 4 * p;   // 0..31
            float v = acc[r] + bv;
            v = v > 0.0f ? v : 0.0f;
            int ba = rowl * (HID * 2) + col * 2;
            ba ^= (rowl & 31) << 4;
            *(bf16*)(sHb + ba) = (bf16)v;
        }
    }
    __syncthreads();

    // ---- phase 2: acc = H @ W2 (A from LDS, barrier-free) ----
#pragma unroll
    for (int r = 0; r < 16; ++r) acc[r] = 0.0f;

    const int hrow = cn;
    const int hswz = (hrow & 31) << 4;
    constexpr int T2 = HID / 16;
#pragma unroll
    for (int t = 0; t < T2; ++t) {
        const int kb = (t * 16 + p * 8) * 2;
        bf16x8 a = *(const bf16x8*)(sHb + ((hrow * (HID * 2) + kb) ^ hswz));
        bf16x8 b = *(const bf16x8*)(Wf2 + ((((t >> 1) * 16 + w * 2 + (t & 1)) * 64) + lane) * 8);
        acc = __builtin_amdgcn_mfma_f32_32x32x16_bf16(a, b, acc, 0, 0, 0);
    }

    // ---- epilogue 2: bias2 + relu + store + slotted colsum ----
    {
        const int col = w * 32 + cn;
        const float bv = bias2[col];
        float part = 0.0f;
#pragma unroll
        for (int r = 0; r < 16; ++r) {
            int rl = (r & 3) + 8 * (r >> 2) + 4 * p;
            int mo = m_base + rl;
            if (mo < M) {
                float v = acc[r] + bv;
                v = v > 0.0f ? v : 0.0f;
                if constexpr (OCHUNK == 0)
                    out_bf[(size_t)mo * HID + col] = (bf16)v;
                else
                    out_bf[((size_t)w * N_NODES + mo) * OCHUNK + cn] = (bf16)v;
                part += v;
            }
        }
        if (colsum8) {
            part += __shfl_xor(part, 32, 64);   // combine the two p-halves
            if (p == 0) atomicAdd(&colsum8[(blockIdx.x & 7) * HID + col], part);
        }
    }
}

// ---------------------------------------------------------------------------
// Graph head: three GEMVs + sum + final GEMV, single block of 256 threads.
// All colsums are 8-slotted.
__global__ void graph_head(const float* __restrict__ cs0_8,
                           const float* __restrict__ cs1_8,
                           const float* __restrict__ cs2_8,
                           const float* __restrict__ g0w, const float* __restrict__ g0b,
                           const float* __restrict__ g1w, const float* __restrict__ g1b,
                           const float* __restrict__ g2w, const float* __restrict__ g2b,
                           const float* __restrict__ glw, const float* __restrict__ glb,
                           float* __restrict__ gvec)
{
    __shared__ float v0[IN_DIM], v1[HID], v2[HID], gs[HID];
    int t = threadIdx.x;
    if (t < IN_DIM) {
        float s = 0.0f;
#pragma unroll
        for (int i = 0; i < 8; ++i) s += cs0_8[i * KPAD1 + t];
        v0[t] = s;
    }
    {
        float s1 = 0.0f, s2 = 0.0f;
#pragma unroll
        for (int i = 0; i < 8; ++i) {
            s1 += cs1_8[i * HID + t];
            s2 += cs2_8[i * HID + t];
        }
        v1[t] = s1;
        v2[t] = s2;
    }
    __syncthreads();

    float a0 = 0.0f, a1 = 0.0f, a2 = 0.0f;
    for (int k = 0; k < IN_DIM; ++k) a0 += v0[k] * g0w[k * HID + t];
    for (int k = 0; k < HID; ++k) {
        a1 += v1[k] * g1w[k * HID + t];
        a2 += v2[k] * g2w[k * HID + t];
    }
    float e0 = fmaxf(a0 + g0b[t], 0.0f);
    float e1 = fmaxf(a1 + g1b[t], 0.0f);
    float e2 = fmaxf(a2 + g2b[t], 0.0f);
    gs[t] = e0 + e1 + e2;
    __syncthreads();

    float a3 = 0.0f;
    for (int k = 0; k < HID; ++k) a3 += gs[k] * glw[k * HID + t];
    gvec[t] = fmaxf(a3 + glb[t], 0.0f);
}

// ---------------------------------------------------------------------------
// out[n,c] = node2[n,c](bf16) + gvec[c] (f32 out); 4 elements per thread.
__global__ void final_add(const bf16* __restrict__ node2,
                          const float* __restrict__ gvec,
                          float* __restrict__ out)
{
    int idx = blockIdx.x * blockDim.x + threadIdx.x;
    size_t base = (size_t)idx * 4;
    int c = (int)(base & (HID - 1));
    bf16x4 v = *(const bf16x4*)(node2 + base);
    f32x4 g = *(const f32x4*)(gvec + c);
    f32x4 o;
#pragma unroll
    for (int j = 0; j < 4; ++j) o[j] = (float)v[j] + g[j];
    *(f32x4*)(out + base) = o;
}

// ---------------------------------------------------------------------------
extern "C" void kernel_launch(void* const* d_in, const int* in_sizes, int n_in,
                              void* d_out, int out_size, void* d_ws, size_t ws_size,
                              hipStream_t stream)
{
    const float* feat = (const float*)d_in[0];
    const int*   ei   = (const int*)d_in[1];
    const int*   src  = ei;
    const int*   dst  = ei + N_EDGES;
    const float* g0w = (const float*)d_in[2],  *g0b = (const float*)d_in[3];
    const float* g1w = (const float*)d_in[4],  *g1b = (const float*)d_in[5];
    const float* g2w = (const float*)d_in[6],  *g2b = (const float*)d_in[7];
    const float* glw = (const float*)d_in[8],  *glb = (const float*)d_in[9];
    const float* m1aw = (const float*)d_in[10], *m1ab = (const float*)d_in[11];
    const float* m1bw = (const float*)d_in[12], *m1bb = (const float*)d_in[13];
    const float* m2aw = (const float*)d_in[14], *m2ab = (const float*)d_in[15];
    const float* m2bw = (const float*)d_in[16], *m2bb = (const float*)d_in[17];
    float* out = (float*)d_out;

    char* ws = (char*)d_ws;
    size_t off = 0;
    auto alloc = [&](size_t bytes) -> void* {
        void* p = ws + off;
        off += (bytes + 255) & ~(size_t)255;
        return p;
    };
    bf16*  featbf = (bf16*)alloc((size_t)N_NODES * KPAD1 * 2);   // tiled [8][N][24]
    bf16*  xsum  = (bf16*) alloc((size_t)N_NODES * KPAD1 * 2);   // tiled [8][N][24]
    bf16*  y2    = (bf16*) alloc((size_t)N_NODES * HID * 2);     // tiled [8][N][32]
    bf16*  node2 = (bf16*) alloc((size_t)N_NODES * HID * 2);     // linear
    bf16*  node1 = (bf16*) alloc((size_t)N_NODES * HID * 2);     // tiled [8][N][32]
    bf16*  Wf1   = (bf16*) alloc((size_t)HID * KPAD1 * 2);       // frag-major
    bf16*  Wf2   = (bf16*) alloc((size_t)HID * HID * 2);
    bf16*  Wf3   = (bf16*) alloc((size_t)HID * HID * 2);
    bf16*  Wf4   = (bf16*) alloc((size_t)HID * HID * 2);
    // deg + csums adjacent -> single memset
    int*   deg   = (int*)  alloc((size_t)N_NODES * 4);
    float* csums = (float*)alloc((8 * KPAD1 + 16 * HID + HID) * 4);
    int*   rowptr  = (int*)alloc((size_t)(N_NODES + 1) * 4);
    int*   cursor  = (int*)alloc((size_t)N_NODES * 4);
    int*   csr_src = (int*)alloc((size_t)N_EDGES * 4);
    float* colsum0_8 = csums;                          // 8 x 192 slots
    float* colsum1_8 = csums + 8 * KPAD1;              // 8 x 256 slots
    float* colsum2_8 = csums + 8 * KPAD1 + 8 * HID;    // 8 x 256 slots
    float* gvec      = csums + 8 * KPAD1 + 16 * HID;   // 256

    const size_t deg_pad = (((size_t)N_NODES * 4) + 255) & ~(size_t)255;
    hipMemsetAsync(deg, 0, deg_pad + (8 * KPAD1 + 16 * HID) * 4, stream);

    // all independent preprocessing in one launch
    prep_all<<<WTB + FPB + DGB, 256, 0, stream>>>(
        m1aw, m1bw, m2aw, m2bw, Wf1, Wf2, Wf3, Wf4,
        feat, featbf, colsum0_8, dst, deg);

    // CSR scan: single kernel
    csr_scan<<<1, 1024, 0, stream>>>(deg, rowptr, cursor);
    // bucketed, XCD-pinned fill
    csr_fill_b<<<((N_EDGES + CFT - 1) / CFT) * 8, 256, 0, stream>>>(src, dst, cursor, csr_src);

    const int gtiles = (N_NODES + 15) / 16;   // 4 nodes/wave x 4 waves
    // xsum = bf16(feat + gather(feat))
    gather_v5<24, 3><<<gtiles * 8, 256, 0, stream>>>(featbf, rowptr, csr_src, xsum);

    const int gblocks = (N_NODES + 31) / 32;   // 1563
    // node1 = relu(relu(xsum@W1+b1)@W2+b2), colsum1 fused
    gemm_mlp32<KPAD1, 24, 32><<<gblocks, 512, 0, stream>>>(
        xsum, Wf1, m1ab, Wf2, m1bb, node1, colsum1_8, N_NODES);
    // y2 = bf16(node1 + gather(node1))
    gather_v5<32, 4><<<gtiles * 8, 256, 0, stream>>>(node1, rowptr, csr_src, y2);
    // node2 = relu(relu(y2@W3+b3)@W4+b4), colsum2 fused
    gemm_mlp32<HID, 32, 0><<<gblocks, 512, 0, stream>>>(
        y2, Wf3, m2ab, Wf4, m2bb, node2, colsum2_8, N_NODES);
    // graph head -> gvec
    graph_head<<<1, 256, 0, stream>>>(colsum0_8, colsum1_8, colsum2_8,
                                      g0w, g0b, g1w, g1b, g2w, g2b, glw, glb, gvec);
    // out = node2 + gvec (wide grid, proven)
    final_add<<<((size_t)N_NODES * HID / 4 + 255) / 256, 256, 0, stream>>>(node2, gvec, out);
    (void)in_sizes; (void)n_in; (void)out_size; (void)ws_size;
}

// Round 14
// 420.759 us; speedup vs baseline: 1.1046x; 1.1010x over previous
//
#include <hip/hip_runtime.h>

#define N_NODES 50000
#define N_EDGES 800000
#define IN_DIM  162
#define HID     256
#define KPAD1   192   // IN_DIM padded to multiple of 32
#define NB      ((N_NODES + 255) / 256)   // 196 scan blocks

typedef __bf16 bf16;
typedef __bf16 bf16x8 __attribute__((ext_vector_type(8)));
typedef __bf16 bf16x4 __attribute__((ext_vector_type(4)));
typedef float  f32x4  __attribute__((ext_vector_type(4)));
typedef float  f32x8  __attribute__((ext_vector_type(8)));
typedef float  f32x16 __attribute__((ext_vector_type(16)));

// ---------------------------------------------------------------------------
// Frag-major weight pack: Wf element E holds the MFMA B-frag element
//   fb = jg*2+kk, E = ((ks*16 + fb)*64 + lane)*8 + e
//   -> W[k][n], n = jg*32 + (lane&31), k = ks*32 + kk*16 + (lane>>5)*8 + e
__device__ __forceinline__ void wf_one(const float* W, bf16* Wf, int K, int E)
{
    int e    = E & 7;
    int lane = (E >> 3) & 63;
    int fb   = (E >> 9) & 15;
    int ks   = E >> 13;
    int n = (fb >> 1) * 32 + (lane & 31);
    int k = ks * 32 + (fb & 1) * 16 + (lane >> 5) * 8 + e;
    Wf[E] = (k < K) ? (bf16)W[(size_t)k * HID + n] : (bf16)0.0f;
}

// ---------------------------------------------------------------------------
// prep_all: one launch, partitioned by block.
#define WTB  ((HID * KPAD1 + 3 * HID * HID + 255) / 256)          // 960
#define FPB  ((N_NODES + 63) / 64)                                // 782
#define DGB  (N_EDGES / 256)                                      // 3125

__global__ void prep_all(const float* __restrict__ m1aw, const float* __restrict__ m1bw,
                         const float* __restrict__ m2aw, const float* __restrict__ m2bw,
                         bf16* __restrict__ Wf1, bf16* __restrict__ Wf2,
                         bf16* __restrict__ Wf3, bf16* __restrict__ Wf4,
                         const float* __restrict__ feat, bf16* __restrict__ featbf,
                         float* __restrict__ colsum8,
                         const int* __restrict__ dst, int* __restrict__ deg)
{
    __shared__ bf16  tile[64][208];   // padded rows (416B stride)
    __shared__ float pcs[4][KPAD1];   // per-rowgroup colsum partials

    const int b   = blockIdx.x;
    const int tid = threadIdx.x;

    if (b < WTB) {
        const int R1 = HID * KPAD1;
        const int R2 = HID * HID;
        int idx = b * 256 + tid;
        if (idx < R1)                 wf_one(m1aw, Wf1, IN_DIM, idx);
        else if (idx < R1 + R2)       wf_one(m1bw, Wf2, HID, idx - R1);
        else if (idx < R1 + 2 * R2)   wf_one(m2aw, Wf3, HID, idx - R1 - R2);
        else if (idx < R1 + 3 * R2)   wf_one(m2bw, Wf4, HID, idx - R1 - 2 * R2);
        return;
    }
    if (b < WTB + FPB) {
        const int fp = b - WTB;
        const int r0 = fp * 64;

        // phase A: thread t<192 owns column-quad ch=t%48 for row-group rg=t/48
        if (tid < 192) {
            const int ch = tid % 48;
            const int rg = tid / 48;
            const int c4 = ch * 4;
            float a0 = 0.0f, a1 = 0.0f, a2 = 0.0f, a3 = 0.0f;
#pragma unroll 4
            for (int k = 0; k < 16; ++k) {
                const int rl = rg * 16 + k;
                const int r  = r0 + rl;
                bf16x4 o;
                if (r < N_NODES) {
                    const float* fr = feat + (size_t)r * IN_DIM;
                    float f0 = (c4 + 0 < IN_DIM) ? fr[c4 + 0] : 0.0f;
                    float f1 = (c4 + 1 < IN_DIM) ? fr[c4 + 1] : 0.0f;
                    float f2 = (c4 + 2 < IN_DIM) ? fr[c4 + 2] : 0.0f;
                    float f3 = (c4 + 3 < IN_DIM) ? fr[c4 + 3] : 0.0f;
                    a0 += f0; a1 += f1; a2 += f2; a3 += f3;
                    o[0] = (bf16)f0; o[1] = (bf16)f1; o[2] = (bf16)f2; o[3] = (bf16)f3;
                } else {
#pragma unroll
                    for (int j = 0; j < 4; ++j) o[j] = (bf16)0.0f;
                }
                *(bf16x4*)(&tile[rl][c4]) = o;
            }
            pcs[rg][c4 + 0] = a0;
            pcs[rg][c4 + 1] = a1;
            pcs[rg][c4 + 2] = a2;
            pcs[rg][c4 + 3] = a3;
        }
        __syncthreads();

        // phase B: group-major coalesced writes: 8 groups x 64 rows x 24 cols
#pragma unroll
        for (int i = 0; i < 6; ++i) {
            int m  = i * 256 + tid;           // [0, 1536)
            int g  = m / 192;
            int wg = m - g * 192;
            int eo = wg * 8;
            int rl = eo / 24;
            int cc = eo - rl * 24;
            int r  = r0 + rl;
            if (r < N_NODES) {
                bf16x8 o = *(const bf16x8*)(&tile[rl][g * 24 + cc]);
                *(bf16x8*)(featbf + ((size_t)g * N_NODES + r0) * 24 + (size_t)rl * 24 + cc) = o;
            }
        }

        // phase C: combine 4 row-group partials, one global atomic per column
        if (tid < IN_DIM) {
            float s = pcs[0][tid] + pcs[1][tid] + pcs[2][tid] + pcs[3][tid];
            atomicAdd(&colsum8[(fp & 7) * KPAD1 + tid], s);
        }
        return;
    }
    {
        int e = (b - WTB - FPB) * 256 + tid;
        atomicAdd(&deg[dst[e]], 1);
    }
}

// ---------------------------------------------------------------------------
// CSR build (3-kernel scan chain — r11-proven ~15us; single-block csr_scan
// was 55us (r13 counters: 1 CU, latency-bound) — reverted).
__global__ void block_degsum(const int* __restrict__ deg, int* __restrict__ bsum)
{
    __shared__ int s[256];
    int t = threadIdx.x;
    int idx = blockIdx.x * 256 + t;
    int v = (idx < N_NODES) ? deg[idx] : 0;
    s[t] = v;
    __syncthreads();
    for (int off = 128; off > 0; off >>= 1) {
        if (t < off) s[t] += s[t + off];
        __syncthreads();
    }
    if (t == 0) bsum[blockIdx.x] = s[0];
}

__global__ void scan_bsum(const int* __restrict__ bsum, int* __restrict__ gsum)
{
    __shared__ int s[256];
    int t = threadIdx.x;
    int v = (t < NB) ? bsum[t] : 0;
    s[t] = v;
    __syncthreads();
    for (int off = 1; off < 256; off <<= 1) {
        int u = (t >= off) ? s[t - off] : 0;
        __syncthreads();
        s[t] += u;
        __syncthreads();
    }
    gsum[t] = s[t] - v;
}

__global__ void block_scan_write(const int* __restrict__ deg, const int* __restrict__ gsum,
                                 int* __restrict__ rowptr, int* __restrict__ cursor)
{
    __shared__ int s[256];
    int t = threadIdx.x;
    int idx = blockIdx.x * 256 + t;
    int v = (idx < N_NODES) ? deg[idx] : 0;
    s[t] = v;
    __syncthreads();
    for (int off = 1; off < 256; off <<= 1) {
        int u = (t >= off) ? s[t - off] : 0;
        __syncthreads();
        s[t] += u;
        __syncthreads();
    }
    int excl = s[t] - v + gsum[blockIdx.x];
    if (idx < N_NODES) {
        rowptr[idx] = excl;
        cursor[idx] = excl;
    }
    if (idx == 0) rowptr[N_NODES] = N_EDGES;
}

// ---------------------------------------------------------------------------
// csr_fill v2: bucketed + XCD-pinned (write-amplification fix, r11-verified).
#define CFT 2048
#define NRANGE ((N_NODES + 7) / 8)   // 6250

__global__ void csr_fill_b(const int* __restrict__ src, const int* __restrict__ dst,
                           int* __restrict__ cursor, int* __restrict__ csr_src)
{
    const int g    = blockIdx.x & 7;
    const int tile = blockIdx.x >> 3;
    const int lo   = g * NRANGE;
    const int hi   = lo + NRANGE;
    const int e0   = tile * CFT;
#pragma unroll
    for (int i = 0; i < CFT / 256; ++i) {
        int e = e0 + i * 256 + threadIdx.x;
        if (e < N_EDGES) {
            int d = dst[e];
            if (d >= lo && d < hi) {
                int p = atomicAdd(&cursor[d], 1);
                csr_src[p] = src[e];
            }
        }
    }
}

// ---------------------------------------------------------------------------
// Gather v5: tiled [8][N][CHUNK] input/output, XCD-pinned groups, in-register
// index list, masked unrolled row-load blocks.
template<int CHUNK, int NACT>
__launch_bounds__(256)
__global__ void gather_v5(const bf16* __restrict__ xin,
                          const int* __restrict__ rowptr,
                          const int* __restrict__ csr_src,
                          bf16* __restrict__ xout)
{
    const int g    = blockIdx.x & 7;
    const int tile = blockIdx.x >> 3;
    const int wv   = threadIdx.x >> 6;
    const int lane = threadIdx.x & 63;
    const int q    = lane >> 4;          // node within wave 0..3
    const int j    = lane & 15;          // idx slot
    const int e    = j >> 2;             // stripe 0..3
    const int c4   = j & 3;              // 16B chunk
    const int n    = tile * 16 + wv * 4 + q;
    const bool valid = (n < N_NODES);
    const bool act   = (c4 < NACT);
    const int  ce    = c4 * 8;
    const bf16* base = xin + (size_t)g * N_NODES * CHUNK;

    int r0 = 0, deg = 0;
    if (valid) {
        r0  = rowptr[n];
        deg = rowptr[n + 1] - r0;
    }

    int a0 = r0 + j;        if (a0 > N_EDGES - 1) a0 = N_EDGES - 1;
    int a1 = r0 + 16 + j;   if (a1 > N_EDGES - 1) a1 = N_EDGES - 1;
    const int i0 = csr_src[a0];
    int i1 = 0;
    if (deg > 16) i1 = csr_src[a1];   // only needed when block 2 fires

    f32x8 acc;
#pragma unroll
    for (int t = 0; t < 8; ++t) acc[t] = 0.0f;
    if (valid && e == 0 && act) {
        bf16x8 t0 = *(const bf16x8*)(base + (size_t)n * CHUNK + ce);
#pragma unroll
        for (int t = 0; t < 8; ++t) acc[t] = (float)t0[t];
    }

    const int lb = lane & ~3;

    // ---- block 1: positions 4e + k ----
    {
        const int s0 = __shfl(i0, lb + 0, 64);
        const int s1 = __shfl(i0, lb + 1, 64);
        const int s2 = __shfl(i0, lb + 2, 64);
        const int s3 = __shfl(i0, lb + 3, 64);
        const int p0 = 4 * e;
        if (act) {
            bf16x8 u0 = *(const bf16x8*)(base + (size_t)s0 * CHUNK + ce);
            bf16x8 u1 = *(const bf16x8*)(base + (size_t)s1 * CHUNK + ce);
            bf16x8 u2 = *(const bf16x8*)(base + (size_t)s2 * CHUNK + ce);
            bf16x8 u3 = *(const bf16x8*)(base + (size_t)s3 * CHUNK + ce);
            if (p0 + 0 < deg) {
#pragma unroll
                for (int t = 0; t < 8; ++t) acc[t] += (float)u0[t];
            }
            if (p0 + 1 < deg) {
#pragma unroll
                for (int t = 0; t < 8; ++t) acc[t] += (float)u1[t];
            }
            if (p0 + 2 < deg) {
#pragma unroll
                for (int t = 0; t < 8; ++t) acc[t] += (float)u2[t];
            }
            if (p0 + 3 < deg) {
#pragma unroll
                for (int t = 0; t < 8; ++t) acc[t] += (float)u3[t];
            }
        }
    }

    // ---- block 2: positions 16 + 4e + k, stripe-gated ----
    {
        const int s0 = __shfl(i1, lb + 0, 64);
        const int s1 = __shfl(i1, lb + 1, 64);
        const int s2 = __shfl(i1, lb + 2, 64);
        const int s3 = __shfl(i1, lb + 3, 64);
        const int p0 = 16 + 4 * e;
        if (act && p0 < deg) {
            bf16x8 u0 = *(const bf16x8*)(base + (size_t)s0 * CHUNK + ce);
            bf16x8 u1 = *(const bf16x8*)(base + (size_t)s1 * CHUNK + ce);
            bf16x8 u2 = *(const bf16x8*)(base + (size_t)s2 * CHUNK + ce);
            bf16x8 u3 = *(const bf16x8*)(base + (size_t)s3 * CHUNK + ce);
            {
#pragma unroll
                for (int t = 0; t < 8; ++t) acc[t] += (float)u0[t];
            }
            if (p0 + 1 < deg) {
#pragma unroll
                for (int t = 0; t < 8; ++t) acc[t] += (float)u1[t];
            }
            if (p0 + 2 < deg) {
#pragma unroll
                for (int t = 0; t < 8; ++t) acc[t] += (float)u2[t];
            }
            if (p0 + 3 < deg) {
#pragma unroll
                for (int t = 0; t < 8; ++t) acc[t] += (float)u3[t];
            }
        }
    }

    // ---- rare tail: deg > 32 ----
    for (int p = 32 + e; p < deg; p += 4) {
        const int s = csr_src[r0 + p];
        if (act) {
            bf16x8 u = *(const bf16x8*)(base + (size_t)s * CHUNK + ce);
#pragma unroll
            for (int t = 0; t < 8; ++t) acc[t] += (float)u[t];
        }
    }

#pragma unroll
    for (int t = 0; t < 8; ++t) {
        acc[t] += __shfl_xor(acc[t], 4, 64);
        acc[t] += __shfl_xor(acc[t], 8, 64);
    }

    if (valid && e == 0 && act) {
        bf16x8 o;
#pragma unroll
        for (int t = 0; t < 8; ++t) o[t] = (bf16)acc[t];
        __builtin_nontemporal_store(o,
            (bf16x8*)(xout + ((size_t)g * N_NODES + n) * CHUNK + ce));
    }
}

// ---------------------------------------------------------------------------
// Fused GIN MLP "gemm_mlp32": out = relu(relu(X@W1+b1)@W2+b2).
// 32-row blocks, 8 waves; wave w owns cols [w*32, w*32+32) -> 32x32 per wave.
// Grid = 1563 blocks = 12512 waves (TLP-maximizing; r7/r8 A/B evidence).
// B-frags coalesced from frag-major Wf (L2-resident); no K-loop barriers.
// H in LDS (16KB), (row&31)<<4 XOR swizzle. colsum 8-slotted [8][HID].
template<int KPAD, int ACHUNK, int OCHUNK>
__launch_bounds__(512)
__global__ void gemm_mlp32(const bf16* __restrict__ X,
                           const bf16* __restrict__ Wf1,
                           const float* __restrict__ bias1,
                           const bf16* __restrict__ Wf2,
                           const float* __restrict__ bias2,
                           bf16* __restrict__ out_bf,
                           float* __restrict__ colsum8,  // [8][HID] or null
                           int M)
{
    __shared__ __align__(128) bf16 sH[32 * HID];   // 16 KB

    const int tid  = threadIdx.x;
    const int w    = tid >> 6;     // col group 0..7
    const int lane = tid & 63;
    const int p    = lane >> 5;
    const int cn   = lane & 31;
    const int m_base = blockIdx.x * 32;

    int arow = m_base + cn;
    if (arow >= M) arow = M - 1;   // clamp (stores guarded)

    f32x16 acc;
#pragma unroll
    for (int r = 0; r < 16; ++r) acc[r] = 0.0f;

    // ---- phase 1: acc = X @ W1 (barrier-free) ----
    constexpr int T1 = KPAD / 16;
#pragma unroll
    for (int t = 0; t < T1; ++t) {
        bf16x8 a;
        {
            const int e = t * 16 + p * 8;
            if constexpr (ACHUNK == 0) {
                a = *(const bf16x8*)(X + (size_t)arow * KPAD + e);
            } else {
                const int gch = e / ACHUNK;
                const int off = e - gch * ACHUNK;
                a = *(const bf16x8*)(X + ((size_t)gch * N_NODES + arow) * ACHUNK + off);
            }
        }
        bf16x8 b = *(const bf16x8*)(Wf1 + ((((t >> 1) * 16 + w * 2 + (t & 1)) * 64) + lane) * 8);
        acc = __builtin_amdgcn_mfma_f32_32x32x16_bf16(a, b, acc, 0, 0, 0);
    }

    // ---- epilogue 1: H = relu(acc + b1) -> LDS, (row&31)<<4 swizzle ----
    char* sHb = (char*)sH;
    {
        const int col = w * 32 + cn;
        const float bv = bias1[col];
#pragma unroll
        for (int r = 0; r < 16; ++r) {
            const int rowl = (r & 3) + 8 * (r >> 2) + 4 * p;   // 0..31
            float v = acc[r] + bv;
            v = v > 0.0f ? v : 0.0f;
            int ba = rowl * (HID * 2) + col * 2;
            ba ^= (rowl & 31) << 4;
            *(bf16*)(sHb + ba) = (bf16)v;
        }
    }
    __syncthreads();

    // ---- phase 2: acc = H @ W2 (A from LDS, barrier-free) ----
#pragma unroll
    for (int r = 0; r < 16; ++r) acc[r] = 0.0f;

    const int hrow = cn;
    const int hswz = (hrow & 31) << 4;
    constexpr int T2 = HID / 16;
#pragma unroll
    for (int t = 0; t < T2; ++t) {
        const int kb = (t * 16 + p * 8) * 2;
        bf16x8 a = *(const bf16x8*)(sHb + ((hrow * (HID * 2) + kb) ^ hswz));
        bf16x8 b = *(const bf16x8*)(Wf2 + ((((t >> 1) * 16 + w * 2 + (t & 1)) * 64) + lane) * 8);
        acc = __builtin_amdgcn_mfma_f32_32x32x16_bf16(a, b, acc, 0, 0, 0);
    }

    // ---- epilogue 2: bias2 + relu + store + slotted colsum ----
    {
        const int col = w * 32 + cn;
        const float bv = bias2[col];
        float part = 0.0f;
#pragma unroll
        for (int r = 0; r < 16; ++r) {
            int rl = (r & 3) + 8 * (r >> 2) + 4 * p;
            int mo = m_base + rl;
            if (mo < M) {
                float v = acc[r] + bv;
                v = v > 0.0f ? v : 0.0f;
                if constexpr (OCHUNK == 0)
                    out_bf[(size_t)mo * HID + col] = (bf16)v;
                else
                    out_bf[((size_t)w * N_NODES + mo) * OCHUNK + cn] = (bf16)v;
                part += v;
            }
        }
        if (colsum8) {
            part += __shfl_xor(part, 32, 64);   // combine the two p-halves
            if (p == 0) atomicAdd(&colsum8[(blockIdx.x & 7) * HID + col], part);
        }
    }
}

// ---------------------------------------------------------------------------
// Graph head: three GEMVs + sum + final GEMV, single block of 256 threads.
// All colsums are 8-slotted.
__global__ void graph_head(const float* __restrict__ cs0_8,
                           const float* __restrict__ cs1_8,
                           const float* __restrict__ cs2_8,
                           const float* __restrict__ g0w, const float* __restrict__ g0b,
                           const float* __restrict__ g1w, const float* __restrict__ g1b,
                           const float* __restrict__ g2w, const float* __restrict__ g2b,
                           const float* __restrict__ glw, const float* __restrict__ glb,
                           float* __restrict__ gvec)
{
    __shared__ float v0[IN_DIM], v1[HID], v2[HID], gs[HID];
    int t = threadIdx.x;
    if (t < IN_DIM) {
        float s = 0.0f;
#pragma unroll
        for (int i = 0; i < 8; ++i) s += cs0_8[i * KPAD1 + t];
        v0[t] = s;
    }
    {
        float s1 = 0.0f, s2 = 0.0f;
#pragma unroll
        for (int i = 0; i < 8; ++i) {
            s1 += cs1_8[i * HID + t];
            s2 += cs2_8[i * HID + t];
        }
        v1[t] = s1;
        v2[t] = s2;
    }
    __syncthreads();

    float a0 = 0.0f, a1 = 0.0f, a2 = 0.0f;
    for (int k = 0; k < IN_DIM; ++k) a0 += v0[k] * g0w[k * HID + t];
    for (int k = 0; k < HID; ++k) {
        a1 += v1[k] * g1w[k * HID + t];
        a2 += v2[k] * g2w[k * HID + t];
    }
    float e0 = fmaxf(a0 + g0b[t], 0.0f);
    float e1 = fmaxf(a1 + g1b[t], 0.0f);
    float e2 = fmaxf(a2 + g2b[t], 0.0f);
    gs[t] = e0 + e1 + e2;
    __syncthreads();

    float a3 = 0.0f;
    for (int k = 0; k < HID; ++k) a3 += gs[k] * glw[k * HID + t];
    gvec[t] = fmaxf(a3 + glb[t], 0.0f);
}

// ---------------------------------------------------------------------------
// out[n,c] = node2[n,c](bf16) + gvec[c] (f32 out); 4 elements per thread.
__global__ void final_add(const bf16* __restrict__ node2,
                          const float* __restrict__ gvec,
                          float* __restrict__ out)
{
    int idx = blockIdx.x * blockDim.x + threadIdx.x;
    size_t base = (size_t)idx * 4;
    int c = (int)(base & (HID - 1));
    bf16x4 v = *(const bf16x4*)(node2 + base);
    f32x4 g = *(const f32x4*)(gvec + c);
    f32x4 o;
#pragma unroll
    for (int j = 0; j < 4; ++j) o[j] = (float)v[j] + g[j];
    *(f32x4*)(out + base) = o;
}

// ---------------------------------------------------------------------------
extern "C" void kernel_launch(void* const* d_in, const int* in_sizes, int n_in,
                              void* d_out, int out_size, void* d_ws, size_t ws_size,
                              hipStream_t stream)
{
    const float* feat = (const float*)d_in[0];
    const int*   ei   = (const int*)d_in[1];
    const int*   src  = ei;
    const int*   dst  = ei + N_EDGES;
    const float* g0w = (const float*)d_in[2],  *g0b = (const float*)d_in[3];
    const float* g1w = (const float*)d_in[4],  *g1b = (const float*)d_in[5];
    const float* g2w = (const float*)d_in[6],  *g2b = (const float*)d_in[7];
    const float* glw = (const float*)d_in[8],  *glb = (const float*)d_in[9];
    const float* m1aw = (const float*)d_in[10], *m1ab = (const float*)d_in[11];
    const float* m1bw = (const float*)d_in[12], *m1bb = (const float*)d_in[13];
    const float* m2aw = (const float*)d_in[14], *m2ab = (const float*)d_in[15];
    const float* m2bw = (const float*)d_in[16], *m2bb = (const float*)d_in[17];
    float* out = (float*)d_out;

    char* ws = (char*)d_ws;
    size_t off = 0;
    auto alloc = [&](size_t bytes) -> void* {
        void* p = ws + off;
        off += (bytes + 255) & ~(size_t)255;
        return p;
    };
    bf16*  featbf = (bf16*)alloc((size_t)N_NODES * KPAD1 * 2);   // tiled [8][N][24]
    bf16*  xsum  = (bf16*) alloc((size_t)N_NODES * KPAD1 * 2);   // tiled [8][N][24]
    bf16*  y2    = (bf16*) alloc((size_t)N_NODES * HID * 2);     // tiled [8][N][32]
    bf16*  node2 = (bf16*) alloc((size_t)N_NODES * HID * 2);     // linear
    bf16*  node1 = (bf16*) alloc((size_t)N_NODES * HID * 2);     // tiled [8][N][32]
    bf16*  Wf1   = (bf16*) alloc((size_t)HID * KPAD1 * 2);       // frag-major
    bf16*  Wf2   = (bf16*) alloc((size_t)HID * HID * 2);
    bf16*  Wf3   = (bf16*) alloc((size_t)HID * HID * 2);
    bf16*  Wf4   = (bf16*) alloc((size_t)HID * HID * 2);
    // deg + csums adjacent -> single memset
    int*   deg   = (int*)  alloc((size_t)N_NODES * 4);
    float* csums = (float*)alloc((8 * KPAD1 + 16 * HID + HID) * 4);
    int*   rowptr  = (int*)alloc((size_t)(N_NODES + 1) * 4);
    int*   cursor  = (int*)alloc((size_t)N_NODES * 4);
    int*   csr_src = (int*)alloc((size_t)N_EDGES * 4);
    int*   bsum    = (int*)alloc(256 * 4);
    int*   gsum    = (int*)alloc(256 * 4);
    float* colsum0_8 = csums;                          // 8 x 192 slots
    float* colsum1_8 = csums + 8 * KPAD1;              // 8 x 256 slots
    float* colsum2_8 = csums + 8 * KPAD1 + 8 * HID;    // 8 x 256 slots
    float* gvec      = csums + 8 * KPAD1 + 16 * HID;   // 256

    const size_t deg_pad = (((size_t)N_NODES * 4) + 255) & ~(size_t)255;
    hipMemsetAsync(deg, 0, deg_pad + (8 * KPAD1 + 16 * HID) * 4, stream);

    // all independent preprocessing in one launch
    prep_all<<<WTB + FPB + DGB, 256, 0, stream>>>(
        m1aw, m1bw, m2aw, m2bw, Wf1, Wf2, Wf3, Wf4,
        feat, featbf, colsum0_8, dst, deg);

    // CSR scan chain (3-kernel, parallel — r11-proven)
    block_degsum<<<NB, 256, 0, stream>>>(deg, bsum);
    scan_bsum<<<1, 256, 0, stream>>>(bsum, gsum);
    block_scan_write<<<NB, 256, 0, stream>>>(deg, gsum, rowptr, cursor);
    // bucketed, XCD-pinned fill
    csr_fill_b<<<((N_EDGES + CFT - 1) / CFT) * 8, 256, 0, stream>>>(src, dst, cursor, csr_src);

    const int gtiles = (N_NODES + 15) / 16;   // 4 nodes/wave x 4 waves
    // xsum = bf16(feat + gather(feat))
    gather_v5<24, 3><<<gtiles * 8, 256, 0, stream>>>(featbf, rowptr, csr_src, xsum);

    const int gblocks = (N_NODES + 31) / 32;   // 1563
    // node1 = relu(relu(xsum@W1+b1)@W2+b2), colsum1 fused
    gemm_mlp32<KPAD1, 24, 32><<<gblocks, 512, 0, stream>>>(
        xsum, Wf1, m1ab, Wf2, m1bb, node1, colsum1_8, N_NODES);
    // y2 = bf16(node1 + gather(node1))
    gather_v5<32, 4><<<gtiles * 8, 256, 0, stream>>>(node1, rowptr, csr_src, y2);
    // node2 = relu(relu(y2@W3+b3)@W4+b4), colsum2 fused
    gemm_mlp32<HID, 32, 0><<<gblocks, 512, 0, stream>>>(
        y2, Wf3, m2ab, Wf4, m2bb, node2, colsum2_8, N_NODES);
    // graph head -> gvec
    graph_head<<<1, 256, 0, stream>>>(colsum0_8, colsum1_8, colsum2_8,
                                      g0w, g0b, g1w, g1b, g2w, g2b, glw, glb, gvec);
    // out = node2 + gvec (wide grid, proven)
    final_add<<<((size_t)N_NODES * HID / 4 + 255) / 256, 256, 0, stream>>>(node2, gvec, out);
    (void)in_sizes; (void)n_in; (void)out_size; (void)ws_size;
}